// Round 1
// baseline (131.147 us; speedup 1.0000x reference)
//
#include <hip/hip_runtime.h>
#include <math.h>

// Problem constants (from setup_inputs): x[B,D] fp32, K=8 bins per column.
#define DD   256
#define KK   8
#define DTILE 64      // d-columns per block
#define ROWS  128     // b-rows per block

// ---------------------------------------------------------------------------
// Setup kernel: one thread per column d. Computes, per sub-bin j in [0,16):
//   out(x) = (A' + B'x) / (C' + D'x)   for x in [s[j], s[j+1])
// where sub-bin 2k is theta in [0,lam_k], 2k+1 is theta in [lam_k,1].
// Coefficients composed in double to avoid cancellation when 1/width is big.
// parG: float4[D*16]  (A',B',C',D') per (d, sub-bin)
// bndG: float [D*15]  interior boundaries s[1..15] per d (s[0]=-3, s[16]=3+eps
//                     are never probed by the 4-step binary search)
// ---------------------------------------------------------------------------
__global__ void spline_setup(const float* __restrict__ uw, const float* __restrict__ uh,
                             const float* __restrict__ ud, const float* __restrict__ ul,
                             float4* __restrict__ parG, float* __restrict__ bndG) {
    int d = blockIdx.x * blockDim.x + threadIdx.x;
    if (d >= DD) return;
    const float* uwd = uw + d * KK;
    const float* uhd = uh + d * KK;
    const float* udd = ud + d * (KK - 1);
    const float* uld = ul + d * KK;

    // softmax (match reference: max-subtracted fp32 exp)
    float mw = -1e30f, mh = -1e30f;
    for (int k = 0; k < KK; ++k) { mw = fmaxf(mw, uwd[k]); mh = fmaxf(mh, uhd[k]); }
    double sw = 0.0, sh = 0.0;
    for (int k = 0; k < KK; ++k) { sw += (double)expf(uwd[k] - mw); sh += (double)expf(uhd[k] - mh); }
    double invsw = 1.0 / sw, invsh = 1.0 / sh;

    double kx[KK + 1], ky[KK + 1], der[KK + 1], lam[KK];
    double cw = 0.0, ch = 0.0;
    kx[0] = -3.0; ky[0] = -3.0;
    for (int k = 0; k < KK; ++k) {
        double wk = 1e-3 + (1.0 - 1e-3 * KK) * ((double)expf(uwd[k] - mw) * invsw);
        double hk = 1e-3 + (1.0 - 1e-3 * KK) * ((double)expf(uhd[k] - mh) * invsh);
        cw += wk; ch += hk;
        kx[k + 1] = 6.0 * cw - 3.0;
        ky[k + 1] = 6.0 * ch - 3.0;
    }
    kx[KK] = 3.0; ky[KK] = 3.0;   // reference forces endpoints before taking diffs
    der[0] = 1.0 - 1e-3; der[KK] = 1.0 - 1e-3;   // pad value 1.0 - MIN_DERIV
    for (int k = 0; k < KK - 1; ++k)
        der[k + 1] = 1e-3 + (double)log1pf(expf(udd[k]));     // MIN_DERIV + softplus
    for (int k = 0; k < KK; ++k)
        lam[k] = 0.025 + 0.95 * (1.0 / (1.0 + (double)expf(-uld[k])));

    for (int k = 0; k < KK; ++k) {
        double wdt = kx[k + 1] - kx[k];
        double hgt = ky[k + 1] - ky[k];
        double d0 = der[k], d1 = der[k + 1], l = lam[k];
        double delta = hgt / wdt;
        double wb = sqrt(d0 / d1);                       // wa = 1
        double wc = (l * d0 + (1.0 - l) * wb * d1) / delta;
        double ya = ky[k], yb = ky[k] + hgt;
        double wcyc = wc * (((1.0 - l) * ya + l * wb * yb) / ((1.0 - l) + l * wb));
        double wbyb = wb * yb;
        double invw = 1.0 / wdt, icw = kx[k];

        // left sub-bin (theta <= l):  num = ya*l + (wcyc-ya)*th ; den = l + (wc-1)*th
        {
            double A = ya * l, P = wcyc - ya, C = l, Q = wc - 1.0;
            double Bp = P * invw, Dp = Q * invw;
            parG[d * 16 + 2 * k] = make_float4((float)(A - Bp * icw), (float)Bp,
                                               (float)(C - Dp * icw), (float)Dp);
        }
        // right sub-bin: num = (wcyc - wbyb*l) + (wbyb-wcyc)*th ; den = (wc - wb*l) + (wb-wc)*th
        {
            double A = wcyc - wbyb * l, P = wbyb - wcyc, C = wc - wb * l, Q = wb - wc;
            double Bp = P * invw, Dp = Q * invw;
            parG[d * 16 + 2 * k + 1] = make_float4((float)(A - Bp * icw), (float)Bp,
                                                   (float)(C - Dp * icw), (float)Dp);
        }
        // boundaries: s[2k]=kx[k], s[2k+1]=kx[k]+l*wdt ; store s[1..15] at [i-1]
        if (k > 0) bndG[d * 15 + (2 * k - 1)] = (float)kx[k];
        bndG[d * 15 + (2 * k)]     = (float)(kx[k] + l * wdt);
    }
}

// ---------------------------------------------------------------------------
// Main kernel: block = 4 waves x 64 lanes. lane -> d within a 64-wide d-tile,
// wave -> row group. Params staged in LDS: par stride 17 float4 (68 floats,
// odd multiple of 4 -> 16B aligned, banks spread), bnd stride 15 (odd).
// ---------------------------------------------------------------------------
__global__ __launch_bounds__(256, 4)
void spline_main(const float* __restrict__ x, const float4* __restrict__ parG,
                 const float* __restrict__ bndG, float* __restrict__ out, int B) {
    __shared__ float4 s_par[DTILE * 17];
    __shared__ float  s_bnd[DTILE * 15];

    const int tid = threadIdx.x;
    const int dbase = blockIdx.x * DTILE;

    for (int i = tid; i < DTILE * 16; i += 256) {
        int ld = i >> 4, j = i & 15;
        s_par[ld * 17 + j] = parG[(size_t)(dbase + ld) * 16 + j];
    }
    for (int i = tid; i < DTILE * 15; i += 256) {
        s_bnd[i] = bndG[(size_t)dbase * 15 + i];   // contiguous slab for the tile
    }
    __syncthreads();

    const int lane = tid & 63;
    const int w    = tid >> 6;
    const int d    = dbase + lane;
    const size_t rowbase = (size_t)(blockIdx.y * ROWS + w * (ROWS / 4)) * DD + d;
    const float* xp = x + rowbase;
    float*       op = out + rowbase;
    const int bb = lane * 15 - 1;   // s[i] lives at s_bnd[bb + i], i in [1,15]
    const int pb = lane * 17;

    for (int it = 0; it < (ROWS / 4) / 4; ++it) {
        float xv[4];
#pragma unroll
        for (int r = 0; r < 4; ++r) xv[r] = xp[(size_t)(it * 4 + r) * DD];
#pragma unroll
        for (int r = 0; r < 4; ++r) {
            const float xo = xv[r];
            const float xc = fminf(fmaxf(xo, -3.0f), 3.0f);
            int j = (xc >= s_bnd[bb + 8]) ? 8 : 0;
            if (xc >= s_bnd[bb + j + 4]) j += 4;
            if (xc >= s_bnd[bb + j + 2]) j += 2;
            if (xc >= s_bnd[bb + j + 1]) j += 1;
            const float4 p = s_par[pb + j];
            const float num = fmaf(p.y, xc, p.x);
            const float den = fmaf(p.w, xc, p.z);
            const float res = __fdividef(num, den);
            const bool inside = (xo >= -3.0f) && (xo <= 3.0f);
            op[(size_t)(it * 4 + r) * DD] = inside ? res : xo;
        }
    }
}

extern "C" void kernel_launch(void* const* d_in, const int* in_sizes, int n_in,
                              void* d_out, int out_size, void* d_ws, size_t ws_size,
                              hipStream_t stream) {
    const float* x  = (const float*)d_in[0];
    const float* uw = (const float*)d_in[1];
    const float* uh = (const float*)d_in[2];
    const float* ud = (const float*)d_in[3];
    const float* ul = (const float*)d_in[4];
    float* outp = (float*)d_out;

    const int B = in_sizes[0] / DD;   // 65536

    float4* parG = (float4*)d_ws;                                  // 256*16*16 = 64 KiB
    float*  bndG = (float*)((char*)d_ws + (size_t)DD * 16 * sizeof(float4)); // +15 KiB

    spline_setup<<<dim3((DD + 63) / 64), dim3(64), 0, stream>>>(uw, uh, ud, ul, parG, bndG);
    spline_main<<<dim3(DD / DTILE, B / ROWS), dim3(256), 0, stream>>>(x, parG, bndG, outp, B);
}